// Round 1
// baseline (1853.643 us; speedup 1.0000x reference)
//
#include <hip/hip_runtime.h>

// HAR LSTM (6-channel): 3 encoders x 2-layer LSTM (H=3) over T=2048, B=1024.
// Structure: grid = 32 blocks, block = (64 lanes = sequences, 3 waves = encoders).
// Each thread owns one (encoder, sequence) recurrence entirely in registers.
// x staged to LDS per 16-step chunk (read once for all 3 encoders); BN+ReLU
// applied per-thread; sum over encoders via LDS block reduce; coalesced float4
// stores of out[b, ch, t].

#define T_LEN 2048
#define BATCH 1024
#define CHUNK 16
#define NCHUNK (T_LEN / CHUNK)

__device__ __forceinline__ float fast_sigmoid(float x) {
    // 1 / (1 + exp(-x)) via v_exp_f32 (2^x) + v_rcp_f32
    float t = __builtin_amdgcn_exp2f(-1.4426950408889634f * x);
    return __builtin_amdgcn_rcpf(1.0f + t);
}

__device__ __forceinline__ float fast_tanh(float x) {
    // tanh(x) = 1 - 2/(exp(2x)+1); saturates gracefully (exp2->inf, rcp->0)
    float t = __builtin_amdgcn_exp2f(2.8853900817779268f * x);
    return 1.0f - 2.0f * __builtin_amdgcn_rcpf(1.0f + t);
}

__launch_bounds__(192, 1)
__global__ void har_lstm_kernel(
    const float* __restrict__ x,     // [B, 6, T]
    const float* __restrict__ Wi0,   // [3, 12, 3]
    const float* __restrict__ Wh0,   // [3, 12, 3]
    const float* __restrict__ bi0,   // [3, 12]
    const float* __restrict__ bh0,   // [3, 12]
    const float* __restrict__ Wi1,
    const float* __restrict__ Wh1,
    const float* __restrict__ bi1,
    const float* __restrict__ bh1,
    const float* __restrict__ bng,   // [T]
    const float* __restrict__ bnb,   // [T]
    const float* __restrict__ bnm,   // [T]
    const float* __restrict__ bnv,   // [T]
    float* __restrict__ out)         // [B, 6, T]
{
    // LDS: x tile [ch][n][t] (17-padded: odd stride -> conflict-free),
    //      partials [e][row=n*3+ch][t] (stride 51 across lanes -> conflict-free),
    //      BN scale/shift per chunk.
    __shared__ float lds_x[3][64][17];
    __shared__ float lds_p[3][192][17];
    __shared__ float lds_sc[CHUNK];
    __shared__ float lds_sh[CHUNK];

    const int lane = threadIdx.x;       // sequence within block
    const int e    = threadIdx.y;       // encoder (one wave per encoder)
    const int n    = blockIdx.x * 64 + lane;   // 0..2047 (acc: <1024, gyr: >=1024)

    const int ob = (n < BATCH) ? n : n - BATCH;     // output batch row
    const int c0 = (n < BATCH) ? 0 : 3;             // input/output channel base

    // per-thread (wave-uniform) weights in registers
    float wi0[12][3], wh0[12][3], wi1[12][3], wh1[12][3], bs0[12], bs1[12];
    #pragma unroll
    for (int g = 0; g < 12; ++g) {
        #pragma unroll
        for (int d = 0; d < 3; ++d) {
            wi0[g][d] = Wi0[e * 36 + g * 3 + d];
            wh0[g][d] = Wh0[e * 36 + g * 3 + d];
            wi1[g][d] = Wi1[e * 36 + g * 3 + d];
            wh1[g][d] = Wh1[e * 36 + g * 3 + d];
        }
        bs0[g] = bi0[e * 12 + g] + bh0[e * 12 + g];
        bs1[g] = bi1[e * 12 + g] + bh1[e * 12 + g];
    }

    // staging: wave e loads input channel (c0 + e) for its lane's sequence
    const float* xrow = x + ((size_t)ob * 6 + c0 + e) * T_LEN;
    float* orow = out + ((size_t)ob * 6 + c0 + e) * T_LEN;

    float h0[3] = {0.f, 0.f, 0.f}, cc0[3] = {0.f, 0.f, 0.f};
    float h1[3] = {0.f, 0.f, 0.f}, cc1[3] = {0.f, 0.f, 0.f};

    #pragma unroll 1
    for (int chunk = 0; chunk < NCHUNK; ++chunk) {
        const int t0 = chunk * CHUNK;

        // ---- stage x tile (coalesced-ish float4 along t) ----
        {
            const float4* src = reinterpret_cast<const float4*>(xrow + t0);
            #pragma unroll
            for (int i = 0; i < 4; ++i) {
                float4 v = src[i];
                lds_x[e][lane][4 * i + 0] = v.x;
                lds_x[e][lane][4 * i + 1] = v.y;
                lds_x[e][lane][4 * i + 2] = v.z;
                lds_x[e][lane][4 * i + 3] = v.w;
            }
        }
        // ---- stage BN scale/shift for this chunk ----
        if (e == 0 && lane < CHUNK) {
            const int t = t0 + lane;
            const float sc = bng[t] * rsqrtf(bnv[t] + 1e-5f);
            lds_sc[lane] = sc;
            lds_sh[lane] = bnb[t] - bnm[t] * sc;
        }
        __syncthreads();

        // ---- 16 recurrence steps ----
        #pragma unroll 2
        for (int tt = 0; tt < CHUNK; ++tt) {
            const float in0 = lds_x[0][lane][tt];
            const float in1 = lds_x[1][lane][tt];
            const float in2 = lds_x[2][lane][tt];

            // layer 0
            float gt[12];
            #pragma unroll
            for (int g = 0; g < 12; ++g) {
                gt[g] = bs0[g]
                      + wi0[g][0] * in0 + wi0[g][1] * in1 + wi0[g][2] * in2
                      + wh0[g][0] * h0[0] + wh0[g][1] * h0[1] + wh0[g][2] * h0[2];
            }
            #pragma unroll
            for (int u = 0; u < 3; ++u) {
                const float ig = fast_sigmoid(gt[u]);
                const float fg = fast_sigmoid(gt[3 + u]);
                const float gg = fast_tanh(gt[6 + u]);
                const float og = fast_sigmoid(gt[9 + u]);
                cc0[u] = fg * cc0[u] + ig * gg;
                h0[u] = og * fast_tanh(cc0[u]);
            }

            // layer 1 (input = h0)
            #pragma unroll
            for (int g = 0; g < 12; ++g) {
                gt[g] = bs1[g]
                      + wi1[g][0] * h0[0] + wi1[g][1] * h0[1] + wi1[g][2] * h0[2]
                      + wh1[g][0] * h1[0] + wh1[g][1] * h1[1] + wh1[g][2] * h1[2];
            }
            #pragma unroll
            for (int u = 0; u < 3; ++u) {
                const float ig = fast_sigmoid(gt[u]);
                const float fg = fast_sigmoid(gt[3 + u]);
                const float gg = fast_tanh(gt[6 + u]);
                const float og = fast_sigmoid(gt[9 + u]);
                cc1[u] = fg * cc1[u] + ig * gg;
                h1[u] = og * fast_tanh(cc1[u]);
            }

            // BN (per t) + ReLU, store per-encoder partial
            const float sc = lds_sc[tt];
            const float sh = lds_sh[tt];
            #pragma unroll
            for (int ch = 0; ch < 3; ++ch) {
                lds_p[e][lane * 3 + ch][tt] = fmaxf(0.0f, h1[ch] * sc + sh);
            }
        }
        __syncthreads();

        // ---- reduce over encoders, store: thread (lane, e) -> (seq=lane, ch=e) ----
        {
            const int row = lane * 3 + e;
            float4* dst = reinterpret_cast<float4*>(orow + t0);
            #pragma unroll
            for (int i = 0; i < 4; ++i) {
                float4 v;
                v.x = (lds_p[0][row][4 * i + 0] + lds_p[1][row][4 * i + 0] + lds_p[2][row][4 * i + 0]) * (1.0f / 3.0f);
                v.y = (lds_p[0][row][4 * i + 1] + lds_p[1][row][4 * i + 1] + lds_p[2][row][4 * i + 1]) * (1.0f / 3.0f);
                v.z = (lds_p[0][row][4 * i + 2] + lds_p[1][row][4 * i + 2] + lds_p[2][row][4 * i + 2]) * (1.0f / 3.0f);
                v.w = (lds_p[0][row][4 * i + 3] + lds_p[1][row][4 * i + 3] + lds_p[2][row][4 * i + 3]) * (1.0f / 3.0f);
                dst[i] = v;
            }
        }
        __syncthreads();
    }
}

extern "C" void kernel_launch(void* const* d_in, const int* in_sizes, int n_in,
                              void* d_out, int out_size, void* d_ws, size_t ws_size,
                              hipStream_t stream) {
    (void)in_sizes; (void)n_in; (void)out_size; (void)d_ws; (void)ws_size;
    const float* x   = (const float*)d_in[0];
    const float* Wi0 = (const float*)d_in[1];
    const float* Wh0 = (const float*)d_in[2];
    const float* bi0 = (const float*)d_in[3];
    const float* bh0 = (const float*)d_in[4];
    const float* Wi1 = (const float*)d_in[5];
    const float* Wh1 = (const float*)d_in[6];
    const float* bi1 = (const float*)d_in[7];
    const float* bh1 = (const float*)d_in[8];
    const float* bng = (const float*)d_in[9];
    const float* bnb = (const float*)d_in[10];
    const float* bnm = (const float*)d_in[11];
    const float* bnv = (const float*)d_in[12];

    har_lstm_kernel<<<dim3(32), dim3(64, 3), 0, stream>>>(
        x, Wi0, Wh0, bi0, bh0, Wi1, Wh1, bi1, bh1, bng, bnb, bnm, bnv,
        (float*)d_out);
}

// Round 2
// 969.665 us; speedup vs baseline: 1.9116x; 1.9116x over previous
//
#include <hip/hip_runtime.h>

// HAR LSTM: 2-lane layer-pipelined split.
// Block = 192 threads = 3 waves (one per encoder e); each wave: lanes 0..31 =
// layer 0 of chains 0..31, lanes 32..63 = layer 1 of the same chains, skewed
// one time-step behind. h0 hand-off via per-wave LDS slot (wave-lockstep, no
// barrier). h1 written to a 32-slot ring; BN+ReLU+mean flushed per chunk with
// a 2-chunk lag. Grid = 64 blocks (32 chains each) -> 192 waves.

#define T_LEN 2048
#define BATCH 1024
#define CHUNK 16
#define NCHUNK 128

__device__ __forceinline__ float fast_sigmoid(float x) {
    float t = __builtin_amdgcn_exp2f(-1.4426950408889634f * x);
    return __builtin_amdgcn_rcpf(1.0f + t);
}
__device__ __forceinline__ float fast_tanh(float x) {
    float t = __builtin_amdgcn_exp2f(2.8853900817779268f * x);
    return 1.0f - 2.0f * __builtin_amdgcn_rcpf(1.0f + t);
}

__launch_bounds__(192, 1)
__global__ void har_lstm_kernel(
    const float* __restrict__ x,     // [B, 6, T]
    const float* __restrict__ Wi0, const float* __restrict__ Wh0,
    const float* __restrict__ bi0, const float* __restrict__ bh0,
    const float* __restrict__ Wi1, const float* __restrict__ Wh1,
    const float* __restrict__ bi1, const float* __restrict__ bh1,
    const float* __restrict__ bng, const float* __restrict__ bnb,
    const float* __restrict__ bnm, const float* __restrict__ bnv,
    float* __restrict__ out)         // [B, 6, T]
{
    // x tile: [chain][17 granules][4] floats -> granule pos (chain+t)&7, ideal for b128
    __shared__ float lds_x[32 * 68];                 // 8704 B
    // h0 hand-off: [wave][lane][4]
    __shared__ float lds_h[3][64 * 4];               // 3072 B
    // h1 out ring: [e][chain][33 granules] = [chain][slot 0..31][4] (+1 granule pad)
    __shared__ float lds_o[3][32 * 132];             // 50688 B
    // total 62464 B < 64 KiB

    const int lane = threadIdx.x;          // 0..63
    const int e    = threadIdx.y;          // 0..2 (wave id = encoder)
    const bool l1  = (lane >= 32);
    const int chain = lane & 31;
    const int n  = blockIdx.x * 32 + chain;
    const int ob = (n < BATCH) ? n : n - BATCH;
    const int c0 = (n < BATCH) ? 0 : 3;

    // per-lane weights: layer 0 for lanes<32, layer 1 for lanes>=32
    const float* Wi = l1 ? Wi1 : Wi0;
    const float* Wh = l1 ? Wh1 : Wh0;
    const float* bi = l1 ? bi1 : bi0;
    const float* bh = l1 ? bh1 : bh0;
    float wi[12][3], wh[12][3], bs[12];
    #pragma unroll
    for (int g = 0; g < 12; ++g) {
        #pragma unroll
        for (int d = 0; d < 3; ++d) {
            wi[g][d] = Wi[e * 36 + g * 3 + d];
            wh[g][d] = Wh[e * 36 + g * 3 + d];
        }
        bs[g] = bi[e * 12 + g] + bh[e * 12 + g];
    }

    // per-lane LDS routing (all byte-level float4-aligned)
    const float* rbase = l1 ? &lds_h[e][(lane - 32) * 4] : &lds_x[chain * 68];
    float*       wbase = l1 ? &lds_o[e][chain * 132]     : &lds_h[e][lane * 4];
    const int rmask = l1 ? 0 : -1;   // layer0 reads advance with t&15
    const int wmask = l1 ? -1 : 0;   // layer1 writes advance with (t-1)&31

    float h[3] = {0.f, 0.f, 0.f}, cc[3] = {0.f, 0.f, 0.f};

    // ---- staging of x chunk c into lds_x ----
    const int tix = threadIdx.y * 64 + threadIdx.x;   // 0..191
    auto stage = [&](int c) {
        #pragma unroll
        for (int k = 0; k < 2; ++k) {
            const int idx = tix + k * 192;     // 0..383
            const int row = idx >> 2;          // 0..95
            const int seg = idx & 3;
            const int cn  = row & 31;
            const int ch  = row >> 5;          // 0..2
            const int nn  = blockIdx.x * 32 + cn;
            const int oo  = (nn < BATCH) ? nn : nn - BATCH;
            const int cc0 = (nn < BATCH) ? 0 : 3;
            const float4 v = *reinterpret_cast<const float4*>(
                x + ((size_t)(oo * 6 + cc0 + ch)) * T_LEN + c * CHUNK + seg * 4);
            const int base = cn * 68 + seg * 16 + ch;   // [chain][t][ch], t granule = seg*4+j
            lds_x[base + 0]  = v.x;
            lds_x[base + 4]  = v.y;
            lds_x[base + 8]  = v.z;
            lds_x[base + 12] = v.w;
        }
    };

    // ---- one recurrence iteration at global step t ----
    auto body = [&](int t) {
        const int roff = ((t & 15) * 4) & rmask;
        const float4 in = *reinterpret_cast<const float4*>(rbase + roff);
        float g[12];
        #pragma unroll
        for (int k = 0; k < 12; ++k) {
            g[k] = bs[k]
                 + wi[k][0] * in.x + wi[k][1] * in.y + wi[k][2] * in.z
                 + wh[k][0] * h[0] + wh[k][1] * h[1] + wh[k][2] * h[2];
        }
        #pragma unroll
        for (int u = 0; u < 3; ++u) {
            const float ig = fast_sigmoid(g[u]);
            const float fg = fast_sigmoid(g[3 + u]);
            const float gg = fast_tanh(g[6 + u]);
            const float og = fast_sigmoid(g[9 + u]);
            cc[u] = fg * cc[u] + ig * gg;
            h[u]  = og * fast_tanh(cc[u]);
        }
        const int woff = (((t + 31) & 31) * 4) & wmask;
        *reinterpret_cast<float4*>(wbase + woff) = make_float4(h[0], h[1], h[2], 0.f);
    };

    // ---- flush chunk f: BN + ReLU + mean over e, store to out ----
    auto flush = [&](int f) {
        const int r    = tix >> 1;          // 0..95
        const int half = (tix & 1) * 8;
        const int ch   = r >> 5;            // 0..2
        const int cn   = r & 31;
        const int nn   = blockIdx.x * 32 + cn;
        const int oo   = (nn < BATCH) ? nn : nn - BATCH;
        const int ccb  = (nn < BATCH) ? 0 : 3;
        const int tb   = f * CHUNK + half;  // 8 consecutive t
        float sc[8], sh[8], res[8];
        #pragma unroll
        for (int q = 0; q < 2; ++q) {
            const float4 gv = *reinterpret_cast<const float4*>(bng + tb + q * 4);
            const float4 vv = *reinterpret_cast<const float4*>(bnv + tb + q * 4);
            const float4 bv = *reinterpret_cast<const float4*>(bnb + tb + q * 4);
            const float4 mv = *reinterpret_cast<const float4*>(bnm + tb + q * 4);
            const float s0 = gv.x * rsqrtf(vv.x + 1e-5f);
            const float s1 = gv.y * rsqrtf(vv.y + 1e-5f);
            const float s2 = gv.z * rsqrtf(vv.z + 1e-5f);
            const float s3 = gv.w * rsqrtf(vv.w + 1e-5f);
            sc[q*4+0]=s0; sc[q*4+1]=s1; sc[q*4+2]=s2; sc[q*4+3]=s3;
            sh[q*4+0]=bv.x - mv.x*s0; sh[q*4+1]=bv.y - mv.y*s1;
            sh[q*4+2]=bv.z - mv.z*s2; sh[q*4+3]=bv.w - mv.w*s3;
        }
        #pragma unroll
        for (int k = 0; k < 8; ++k) {
            const int slot = (tb + k) & 31;
            float s = 0.f;
            #pragma unroll
            for (int ee = 0; ee < 3; ++ee) {
                const float v = lds_o[ee][cn * 132 + slot * 4 + ch];
                s += fmaxf(0.f, fmaf(v, sc[k], sh[k]));
            }
            res[k] = s * (1.0f / 3.0f);
        }
        float* orow = out + ((size_t)(oo * 6 + ccb + ch)) * T_LEN + tb;
        *reinterpret_cast<float4*>(orow)     = make_float4(res[0], res[1], res[2], res[3]);
        *reinterpret_cast<float4*>(orow + 4) = make_float4(res[4], res[5], res[6], res[7]);
    };

    // ================= schedule =================
    stage(0);
    __syncthreads();

    // chunk 0 with iter-0 fixup (layer-1 lanes computed garbage at t=0)
    body(0);
    if (l1) { h[0]=h[1]=h[2]=0.f; cc[0]=cc[1]=cc[2]=0.f; }
    #pragma unroll 4
    for (int tt = 1; tt < CHUNK; ++tt) body(tt);

    #pragma unroll 1
    for (int c = 1; c < NCHUNK; ++c) {
        __syncthreads();
        stage(c);
        if (c >= 2) flush(c - 2);
        __syncthreads();
        const int tb = c * CHUNK;
        #pragma unroll 4
        for (int tt = 0; tt < CHUNK; ++tt) body(tb + tt);
    }

    __syncthreads();
    flush(NCHUNK - 2);
    __syncthreads();
    body(T_LEN);            // epilogue: layer-1 completes step T-1 (layer-0 result unused)
    __syncthreads();
    flush(NCHUNK - 1);
}

extern "C" void kernel_launch(void* const* d_in, const int* in_sizes, int n_in,
                              void* d_out, int out_size, void* d_ws, size_t ws_size,
                              hipStream_t stream) {
    (void)in_sizes; (void)n_in; (void)out_size; (void)d_ws; (void)ws_size;
    const float* x   = (const float*)d_in[0];
    const float* Wi0 = (const float*)d_in[1];
    const float* Wh0 = (const float*)d_in[2];
    const float* bi0 = (const float*)d_in[3];
    const float* bh0 = (const float*)d_in[4];
    const float* Wi1 = (const float*)d_in[5];
    const float* Wh1 = (const float*)d_in[6];
    const float* bi1 = (const float*)d_in[7];
    const float* bh1 = (const float*)d_in[8];
    const float* bng = (const float*)d_in[9];
    const float* bnb = (const float*)d_in[10];
    const float* bnm = (const float*)d_in[11];
    const float* bnv = (const float*)d_in[12];

    har_lstm_kernel<<<dim3(64), dim3(64, 3), 0, stream>>>(
        x, Wi0, Wh0, bi0, bh0, Wi1, Wh1, bi1, bh1, bng, bnb, bnm, bnv,
        (float*)d_out);
}

// Round 3
// 420.772 us; speedup vs baseline: 4.4053x; 2.3045x over previous
//
#include <hip/hip_runtime.h>

// HAR LSTM: unit-split quads. Each chain-layer (n, e, layer) lives on a 4-lane
// quad: lane ql computes unit u = ql%3 (lane 3 duplicates unit 0). Per step:
// 4 gates (24 FMA) + 5 activations (10 trans). h exchange via DPP quad_perm
// (relative weight-column permutation keeps code lane-uniform); layer0->layer1
// handoff via __shfl_xor(.,32) (layer-1 quads are partner+32). 1-step layer
// skew as round 2. Wave = 8 chains x 2 layers; block = 3 e-waves; grid = 256
// -> 768 waves. BN coefs precomputed in LDS; out ring + lag-2 flush.

#define T_LEN 2048
#define BATCH 1024
#define CHUNK 16
#define NCHUNK 128
#define NN 8

__device__ __forceinline__ float fast_sigmoid(float x) {
    float t = __builtin_amdgcn_exp2f(-1.4426950408889634f * x);
    return __builtin_amdgcn_rcpf(1.0f + t);
}
__device__ __forceinline__ float fast_tanh(float x) {
    float t = __builtin_amdgcn_exp2f(2.8853900817779268f * x);
    return 1.0f - 2.0f * __builtin_amdgcn_rcpf(1.0f + t);
}

// quad_perm DPP: dst lane k of each quad reads lane sel[k].
// A: [1,2,0,1] -> next unit;  B: [2,0,1,2] -> next-next unit.
template<int CTRL>
__device__ __forceinline__ float dpp_qp(float v) {
    int i = __float_as_int(v);
    i = __builtin_amdgcn_update_dpp(i, i, CTRL, 0xF, 0xF, false);
    return __int_as_float(i);
}
#define DPP_A 73    // 1 | 2<<2 | 0<<4 | 1<<6
#define DPP_B 146   // 2 | 0<<2 | 1<<4 | 2<<6

__launch_bounds__(192, 1)
__global__ void har_lstm_kernel(
    const float* __restrict__ x,
    const float* __restrict__ Wi0, const float* __restrict__ Wh0,
    const float* __restrict__ bi0, const float* __restrict__ bh0,
    const float* __restrict__ Wi1, const float* __restrict__ Wh1,
    const float* __restrict__ bi1, const float* __restrict__ bh1,
    const float* __restrict__ bng, const float* __restrict__ bnb,
    const float* __restrict__ bnm, const float* __restrict__ bnv,
    float* __restrict__ out)
{
    __shared__ __align__(16) float lds_x[NN * 68];        // [i][t][ch pad4], stride 68: bank-shifted
    __shared__ __align__(16) float lds_o[3 * NN * 132];   // [e][i][slot*4+u], stride 132
    __shared__ __align__(16) float lds_bn[T_LEN * 2];     // [t][sc,sh]  16 KB
    __shared__ __align__(16) float lds_dump[64];

    const int lane = threadIdx.x;            // 0..63
    const int e    = threadIdx.y;            // 0..2
    const int tix  = e * 64 + lane;
    const int q    = lane >> 2;
    const int ql   = lane & 3;
    const bool l1  = (q >= 8);
    const int i    = l1 ? (q - 8) : q;       // chain index within block
    const int u    = (ql < 3) ? ql : 0;      // unit (lane 3 dups unit 0)

    // ---- BN coefficient precompute (once) ----
    for (int idx = tix; idx < T_LEN; idx += 192) {
        const float sc = bng[idx] * rsqrtf(bnv[idx] + 1e-5f);
        lds_bn[2 * idx]     = sc;
        lds_bn[2 * idx + 1] = bnb[idx] - bnm[idx] * sc;
    }

    // ---- per-lane weights (4 gate rows of this unit) ----
    const float* Wi = l1 ? Wi1 : Wi0;
    const float* Wh = l1 ? Wh1 : Wh0;
    const float* bi = l1 ? bi1 : bi0;
    const float* bh = l1 ? bh1 : bh0;
    float wi[4][3], wh[4][3], bs[4];
    #pragma unroll
    for (int g = 0; g < 4; ++g) {
        const int row = g * 3 + u;           // PyTorch gate order i,f,g,o
        #pragma unroll
        for (int k = 0; k < 3; ++k) {
            const int cr = (u + k) % 3;      // relative column
            wi[g][k] = Wi[e * 36 + row * 3 + (l1 ? cr : k)];  // l1 input arrives rel-order
            wh[g][k] = Wh[e * 36 + row * 3 + cr];             // state always rel-order
        }
        bs[g] = bi[e * 12 + row] + bh[e * 12 + row];
    }

    // DS routing: l0 reads x tile, writes dump; l1 reads dump, writes out ring
    const float* rbase = l1 ? lds_dump : &lds_x[i * 68];
    float*       wbase = l1 ? &lds_o[(e * NN + i) * 132 + ql] : &lds_dump[lane];
    const int rmask = l1 ? 0 : -1;
    const int wmask = l1 ? -1 : 0;

    float hown = 0.f, c = 0.f;

    auto stage = [&](int cnk) {
        if (tix < 96) {
            const int row = tix >> 2;        // 0..23
            const int seg = tix & 3;
            const int ch  = row >> 3;        // 0..2
            const int ii  = row & 7;
            const int n   = blockIdx.x * NN + ii;
            const int b   = (n < BATCH) ? n : n - BATCH;
            const int cb  = (n < BATCH) ? 0 : 3;
            const float4 v = *reinterpret_cast<const float4*>(
                x + ((size_t)(b * 6 + cb + ch)) * T_LEN + cnk * CHUNK + seg * 4);
            float* d = &lds_x[ii * 68 + seg * 16 + ch];
            d[0] = v.x; d[4] = v.y; d[8] = v.z; d[12] = v.w;
        }
    };

    auto body = [&](int t) {
        // state exchange within quad (rel order: own, next, next2)
        const float h1r = dpp_qp<DPP_A>(hown);
        const float h2r = dpp_qp<DPP_B>(hown);
        // layer0 -> layer1 handoff (partner quad is lane-32 below)
        const float s0 = __shfl_xor(hown, 32);
        const float s1 = dpp_qp<DPP_A>(s0);
        const float s2 = dpp_qp<DPP_B>(s0);
        // input vector
        const float4 xv = *reinterpret_cast<const float4*>(rbase + (((t & 15) * 4) & rmask));
        const float in0 = l1 ? s0 : xv.x;
        const float in1 = l1 ? s1 : xv.y;
        const float in2 = l1 ? s2 : xv.z;

        float ga[4];
        #pragma unroll
        for (int g = 0; g < 4; ++g) {
            const float p0 = fmaf(wi[g][0], in0, bs[g]);
            const float p1 = fmaf(wi[g][1], in1, wi[g][2] * in2);
            const float p2 = fmaf(wh[g][0], hown, wh[g][1] * h1r);
            const float p3 = wh[g][2] * h2r;
            ga[g] = (p0 + p1) + (p2 + p3);
        }
        const float ig = fast_sigmoid(ga[0]);
        const float fg = fast_sigmoid(ga[1]);
        const float gg = fast_tanh(ga[2]);
        const float og = fast_sigmoid(ga[3]);
        c = fmaf(fg, c, ig * gg);
        hown = og * fast_tanh(c);
        // l1: h1(t-1) -> ring slot (t-1)&31 ; l0: dump
        wbase[(((t + 31) & 31) * 4) & wmask] = hown;
    };

    auto flush = [&](int f) {
        const int row = tix >> 3;            // 0..23
        const int tp  = (tix & 7) * 2;
        const int uu  = row >> 3;            // 0..2
        const int ii  = row & 7;
        const int n   = blockIdx.x * NN + ii;
        const int b   = (n < BATCH) ? n : n - BATCH;
        const int cb  = (n < BATCH) ? 0 : 3;
        const int t   = f * CHUNK + tp;
        const float4 bn = *reinterpret_cast<const float4*>(&lds_bn[t * 2]);
        float r0 = 0.f, r1 = 0.f;
        #pragma unroll
        for (int ee = 0; ee < 3; ++ee) {
            const float* base = &lds_o[(ee * NN + ii) * 132 + uu];
            r0 += fmaxf(0.f, fmaf(base[((t) & 31) * 4],     bn.x, bn.y));
            r1 += fmaxf(0.f, fmaf(base[((t + 1) & 31) * 4], bn.z, bn.w));
        }
        float* orow = out + ((size_t)(b * 6 + cb + uu)) * T_LEN + t;
        *reinterpret_cast<float2*>(orow) = make_float2(r0 * (1.f / 3.f), r1 * (1.f / 3.f));
    };

    // ================= schedule =================
    stage(0);
    __syncthreads();

    body(0);
    if (l1) { hown = 0.f; c = 0.f; }   // discard layer-1's tau=-1 garbage
    #pragma unroll 4
    for (int tt = 1; tt < CHUNK; ++tt) body(tt);

    #pragma unroll 1
    for (int cnk = 1; cnk < NCHUNK; ++cnk) {
        __syncthreads();
        stage(cnk);
        if (cnk >= 2) flush(cnk - 2);
        __syncthreads();
        const int tb = cnk * CHUNK;
        #pragma unroll 4
        for (int tt = 0; tt < CHUNK; ++tt) body(tb + tt);
    }

    __syncthreads();
    flush(NCHUNK - 2);
    __syncthreads();
    body(T_LEN);                       // layer-1 completes step T-1
    __syncthreads();
    flush(NCHUNK - 1);
}

extern "C" void kernel_launch(void* const* d_in, const int* in_sizes, int n_in,
                              void* d_out, int out_size, void* d_ws, size_t ws_size,
                              hipStream_t stream) {
    (void)in_sizes; (void)n_in; (void)out_size; (void)d_ws; (void)ws_size;
    const float* x   = (const float*)d_in[0];
    const float* Wi0 = (const float*)d_in[1];
    const float* Wh0 = (const float*)d_in[2];
    const float* bi0 = (const float*)d_in[3];
    const float* bh0 = (const float*)d_in[4];
    const float* Wi1 = (const float*)d_in[5];
    const float* Wh1 = (const float*)d_in[6];
    const float* bi1 = (const float*)d_in[7];
    const float* bh1 = (const float*)d_in[8];
    const float* bng = (const float*)d_in[9];
    const float* bnb = (const float*)d_in[10];
    const float* bnm = (const float*)d_in[11];
    const float* bnv = (const float*)d_in[12];

    har_lstm_kernel<<<dim3(256), dim3(64, 3), 0, stream>>>(
        x, Wi0, Wh0, bi0, bh0, Wi1, Wh1, bi1, bh1, bng, bnb, bnm, bnv,
        (float*)d_out);
}

// Round 4
// 403.818 us; speedup vs baseline: 4.5903x; 1.0420x over previous
//
#include <hip/hip_runtime.h>

// HAR LSTM, gate-split layout.
// 8-lane group = one (chain, encoder, layer): lane 2u+p computes gate rows
// {i_u,f_u} (p=0) or {g_u,o_u} (p=1); lanes 6,7 duplicate unit 0. Wave =
// 8 groups = 4 chains x 2 layers (layer L = group&1, partner group = ^1, i.e.
// lanes ^8). Block = 3 waves (encoder e = threadIdx.y), 4 chains/block ->
// grid 512, 1536 waves (~1.5 waves/SIMD -> real TLP).
// Per step: 6 ds_bpermute gather own-h trio + partner-layer h trio (l0->l1
// handoff, register-level, race-free in-wave), 12 FMA gates (act scales folded
// into weights), unified activation A + B*rcp(1+exp2(pre)), DPP quad-swap to
// exchange (i,f)<->(g,o), c/h computed duplicated on both lanes of the pair.
// 1-step layer skew; h1 -> 32-slot LDS ring; BN+ReLU+mean flush with lag 2.

#define T_LEN 2048
#define BATCH 1024
#define CHUNK 16
#define NCHUNK 128
#define NCH 4   // chains per block

__device__ __forceinline__ float dpp_swap(float v) {
    // quad_perm [1,0,3,2]: swap adjacent lane pairs
    int i = __float_as_int(v);
    i = __builtin_amdgcn_update_dpp(i, i, 177, 0xF, 0xF, false);
    return __int_as_float(i);
}
__device__ __forceinline__ float bperm(int byteidx, float v) {
    return __int_as_float(__builtin_amdgcn_ds_bpermute(byteidx, __float_as_int(v)));
}

__launch_bounds__(192, 2)
__global__ void har_lstm_kernel(
    const float* __restrict__ x,
    const float* __restrict__ Wi0, const float* __restrict__ Wh0,
    const float* __restrict__ bi0, const float* __restrict__ bh0,
    const float* __restrict__ Wi1, const float* __restrict__ Wh1,
    const float* __restrict__ bi1, const float* __restrict__ bh1,
    const float* __restrict__ bng, const float* __restrict__ bnb,
    const float* __restrict__ bnm, const float* __restrict__ bnv,
    float* __restrict__ out)
{
    __shared__ __align__(16) float lds_x[NCH * 52];        // [i][ch][16 +4 pad]
    __shared__ __align__(16) float lds_o[3 * NCH * 132];   // [(e,i)][slot*4+u]
    __shared__ __align__(16) float lds_bn[T_LEN * 2];      // [t][sc,sh]
    __shared__ float lds_dump[3 * 64];

    const int lane = threadIdx.x;       // 0..63
    const int e    = threadIdx.y;       // 0..2
    const int tix  = e * 64 + lane;

    const int grp = lane >> 3;          // 0..7
    const int L   = grp & 1;            // 0 = layer0, 1 = layer1
    const int ci  = grp >> 1;           // chain in block 0..3
    const int sub = lane & 7;
    const int su  = (sub > 5) ? (sub - 6) : sub;   // lanes 6,7 dup unit 0
    const int u   = su >> 1;            // unit 0..2
    const int p   = su & 1;             // 0: rows i,f ; 1: rows g,o

    // ---- BN (scale, shift) table ----
    for (int idx = tix; idx < T_LEN; idx += 192) {
        const float sc = bng[idx] * rsqrtf(bnv[idx] + 1e-5f);
        lds_bn[2 * idx]     = sc;
        lds_bn[2 * idx + 1] = bnb[idx] - bnm[idx] * sc;
    }

    // ---- per-lane weights, activation scales folded in ----
    const float LOG2E = 1.4426950408889634f;
    const int   rowA = (p == 0) ? u : (6 + u);         // i_u  or g_u
    const int   rowB = (p == 0) ? (3 + u) : (9 + u);   // f_u  or o_u
    const float sA = (p == 0) ? -LOG2E : 2.0f * LOG2E; // sigmoid vs tanh pre-scale
    const float sB = -LOG2E;
    const float AA = (p == 0) ? 0.f : 1.f;             // act = AA + BA*rcp(1+exp2(pre))
    const float BA = (p == 0) ? 1.f : -2.f;
    const float* Wi = L ? Wi1 : Wi0;
    const float* Wh = L ? Wh1 : Wh0;
    const float* bi = L ? bi1 : bi0;
    const float* bh = L ? bh1 : bh0;
    float wiA[3], whA[3], wiB[3], whB[3];
    #pragma unroll
    for (int k = 0; k < 3; ++k) {
        wiA[k] = sA * Wi[e * 36 + rowA * 3 + k];
        whA[k] = sA * Wh[e * 36 + rowA * 3 + k];
        wiB[k] = sB * Wi[e * 36 + rowB * 3 + k];
        whB[k] = sB * Wh[e * 36 + rowB * 3 + k];
    }
    const float bsA = sA * (bi[e * 12 + rowA] + bh[e * 12 + rowA]);
    const float bsB = sB * (bi[e * 12 + rowB] + bh[e * 12 + rowB]);

    // ---- bpermute byte indices: own group h trio + partner group h trio ----
    const int gb = (lane & 0x38) << 2;   // group base * 4 bytes
    const int pb = gb ^ 32;              // partner group (lanes ^ 8)

    // ---- output routing ----
    const int n  = blockIdx.x * NCH + ci;
    const int b  = (n < BATCH) ? n : n - BATCH;
    const int cb = (n < BATCH) ? 0 : 3;
    const bool real = (L == 1) && (p == 0) && (sub < 6);
    float* wbase = real ? &lds_o[(e * NCH + ci) * 132 + u] : &lds_dump[e * 64 + lane];
    const int wmask = real ? -1 : 0;

    float h = 0.f, c = 0.f;

    auto stage = [&](int cnk) {
        if (tix < 48) {
            const int seg = tix & 3;
            const int r   = tix >> 2;    // 0..11
            const int ii  = r & 3;
            const int ch  = r >> 2;      // 0..2
            const int nn  = blockIdx.x * NCH + ii;
            const int bb  = (nn < BATCH) ? nn : nn - BATCH;
            const int cc  = (nn < BATCH) ? 0 : 3;
            const float4 v = *reinterpret_cast<const float4*>(
                x + ((size_t)(bb * 6 + cc + ch)) * T_LEN + cnk * CHUNK + seg * 4);
            *reinterpret_cast<float4*>(&lds_x[ii * 52 + ch * 16 + seg * 4]) = v;
        }
    };

    auto ldx4 = [&](int m, int ch) -> float4 {
        return *reinterpret_cast<const float4*>(&lds_x[ci * 52 + ch * 16 + m * 4]);
    };

    auto body = [&](int t, float x0, float x1, float x2) {
        // register-level gathers (wave-wide, race-free)
        const float h0r = bperm(gb,      h);
        const float h1r = bperm(gb + 8,  h);
        const float h2r = bperm(gb + 16, h);
        const float s0  = bperm(pb,      h);
        const float s1  = bperm(pb + 8,  h);
        const float s2  = bperm(pb + 16, h);
        const float in0 = L ? s0 : x0;
        const float in1 = L ? s1 : x1;
        const float in2 = L ? s2 : x2;
        const float gA = fmaf(wiA[0], in0, fmaf(wiA[1], in1, fmaf(wiA[2], in2,
                         fmaf(whA[0], h0r, fmaf(whA[1], h1r, fmaf(whA[2], h2r, bsA))))));
        const float gB = fmaf(wiB[0], in0, fmaf(wiB[1], in1, fmaf(wiB[2], in2,
                         fmaf(whB[0], h0r, fmaf(whB[1], h1r, fmaf(whB[2], h2r, bsB))))));
        const float vA = fmaf(BA, __builtin_amdgcn_rcpf(1.f + __builtin_amdgcn_exp2f(gA)), AA);
        const float vB = __builtin_amdgcn_rcpf(1.f + __builtin_amdgcn_exp2f(gB));
        const float wA = dpp_swap(vA);
        const float wB = dpp_swap(vB);
        const float ig = p ? wA : vA;
        const float fg = p ? wB : vB;
        const float gg = p ? vA : wA;
        const float og = p ? vB : wB;
        c = fmaf(fg, c, ig * gg);
        const float tc = __builtin_amdgcn_exp2f(2.8853900817779268f * c);
        const float th = fmaf(-2.f, __builtin_amdgcn_rcpf(1.f + tc), 1.f);
        h = og * th;
        wbase[(((t + 31) & 31) * 4) & wmask] = h;   // l1/p0: h1(t-1) -> ring
    };

    auto flush = [&](int f) {
        const int tt = tix & 15;
        const int r  = tix >> 4;         // 0..11
        const int ii = r & 3;
        const int uu = r >> 2;           // 0..2
        const int nn = blockIdx.x * NCH + ii;
        const int bb = (nn < BATCH) ? nn : nn - BATCH;
        const int cc = (nn < BATCH) ? 0 : 3;
        const int t  = f * CHUNK + tt;
        const int slot = t & 31;
        const float sc = lds_bn[2 * t];
        const float sh = lds_bn[2 * t + 1];
        float s = 0.f;
        #pragma unroll
        for (int ee = 0; ee < 3; ++ee)
            s += fmaxf(0.f, fmaf(lds_o[(ee * NCH + ii) * 132 + slot * 4 + uu], sc, sh));
        out[((size_t)(bb * 6 + cc + uu)) * T_LEN + t] = s * (1.f / 3.f);
    };

    // ================= schedule =================
    stage(0);
    __syncthreads();

    // chunk 0 (with layer-1 tau=-1 garbage reset after first step)
    #pragma unroll
    for (int m = 0; m < 4; ++m) {
        const float4 q0 = ldx4(m, 0), q1 = ldx4(m, 1), q2 = ldx4(m, 2);
        #pragma unroll
        for (int s = 0; s < 4; ++s) {
            const float a0 = (s == 0) ? q0.x : (s == 1) ? q0.y : (s == 2) ? q0.z : q0.w;
            const float a1 = (s == 0) ? q1.x : (s == 1) ? q1.y : (s == 2) ? q1.z : q1.w;
            const float a2 = (s == 0) ? q2.x : (s == 1) ? q2.y : (s == 2) ? q2.z : q2.w;
            body(m * 4 + s, a0, a1, a2);
            if (m == 0 && s == 0) { if (L) { h = 0.f; c = 0.f; } }
        }
    }

    #pragma unroll 1
    for (int cnk = 1; cnk < NCHUNK; ++cnk) {
        __syncthreads();
        stage(cnk);
        if (cnk >= 2) flush(cnk - 2);
        __syncthreads();
        const int tb = cnk * CHUNK;
        #pragma unroll
        for (int m = 0; m < 4; ++m) {
            const float4 q0 = ldx4(m, 0), q1 = ldx4(m, 1), q2 = ldx4(m, 2);
            #pragma unroll
            for (int s = 0; s < 4; ++s) {
                const float a0 = (s == 0) ? q0.x : (s == 1) ? q0.y : (s == 2) ? q0.z : q0.w;
                const float a1 = (s == 0) ? q1.x : (s == 1) ? q1.y : (s == 2) ? q1.z : q1.w;
                const float a2 = (s == 0) ? q2.x : (s == 1) ? q2.y : (s == 2) ? q2.z : q2.w;
                body(tb + m * 4 + s, a0, a1, a2);
            }
        }
    }

    __syncthreads();
    flush(NCHUNK - 2);
    __syncthreads();
    body(T_LEN, 0.f, 0.f, 0.f);   // layer-1 completes step T-1
    __syncthreads();
    flush(NCHUNK - 1);
}

extern "C" void kernel_launch(void* const* d_in, const int* in_sizes, int n_in,
                              void* d_out, int out_size, void* d_ws, size_t ws_size,
                              hipStream_t stream) {
    (void)in_sizes; (void)n_in; (void)out_size; (void)d_ws; (void)ws_size;
    const float* x   = (const float*)d_in[0];
    const float* Wi0 = (const float*)d_in[1];
    const float* Wh0 = (const float*)d_in[2];
    const float* bi0 = (const float*)d_in[3];
    const float* bh0 = (const float*)d_in[4];
    const float* Wi1 = (const float*)d_in[5];
    const float* Wh1 = (const float*)d_in[6];
    const float* bi1 = (const float*)d_in[7];
    const float* bh1 = (const float*)d_in[8];
    const float* bng = (const float*)d_in[9];
    const float* bnb = (const float*)d_in[10];
    const float* bnm = (const float*)d_in[11];
    const float* bnv = (const float*)d_in[12];

    har_lstm_kernel<<<dim3(512), dim3(64, 3), 0, stream>>>(
        x, Wi0, Wh0, bi0, bh0, Wi1, Wh1, bi1, bh1, bng, bnb, bnm, bnv,
        (float*)d_out);
}